// Round 2
// baseline (171.399 us; speedup 1.0000x reference)
//
#include <hip/hip_runtime.h>

#define BB 4
#define TQ 512
#define TK 512
#define DQ 512
#define UU 256
#define CSC 2.8853900817779268f   // 2*log2(e), folded into projections: x = 2log2e*(q+k)
#define L2E 1.4426950408889634f
#define RQ 4   // q-rows per attn block
#define RM 8   // A-rows per proj block

__device__ __forceinline__ float fexp2(float x) { return __builtin_amdgcn_exp2f(x); }
__device__ __forceinline__ float frcp(float x)  { return __builtin_amdgcn_rcpf(x); }

// C = CSC*(A @ W), LDS-free. A:[M,K] row-major (uniform scalar loads),
// W:[K,N] row-major (coalesced, L2-resident). thread = n column, block = RM rows.
__global__ __launch_bounds__(256) void proj(
    const float* __restrict__ Aq, const float* __restrict__ Av,
    const float* __restrict__ W1, const float* __restrict__ W2,
    float* __restrict__ Cq, float* __restrict__ Ck)
{
    const float* A; const float* W; float* C;
    if (blockIdx.z == 0) { A = Aq; W = W1; C = Cq; }
    else                 { A = Av; W = W2; C = Ck; }

    const int n  = threadIdx.x;            // 0..255 == UU
    const int m0 = blockIdx.x * RM;
    const float* a0 = A + (size_t)m0 * DQ;

    float acc[RM] = {};
    for (int k = 0; k < DQ; k += 4) {
        const float w0 = W[(size_t)(k + 0) * UU + n];
        const float w1 = W[(size_t)(k + 1) * UU + n];
        const float w2 = W[(size_t)(k + 2) * UU + n];
        const float w3 = W[(size_t)(k + 3) * UU + n];
        #pragma unroll
        for (int r = 0; r < RM; r++) {
            const float4 a = *(const float4*)&a0[(size_t)r * DQ + k];  // wave-uniform
            acc[r] = fmaf(a.x, w0, fmaf(a.y, w1, fmaf(a.z, w2, fmaf(a.w, w3, acc[r]))));
        }
    }
    #pragma unroll
    for (int r = 0; r < RM; r++)
        C[(size_t)(m0 + r) * UU + n] = CSC * acc[r];
}

// kT[b][u][j] = kp[b][j][u]
__global__ __launch_bounds__(256) void transpose_k(
    const float* __restrict__ kp, float* __restrict__ kT)
{
    __shared__ float tile[32][33];
    const int b  = blockIdx.z;
    const int j0 = blockIdx.x * 32;
    const int u0 = blockIdx.y * 32;
    const int tx = threadIdx.x;   // 0..31
    const int ty = threadIdx.y;   // 0..7
    #pragma unroll
    for (int r = 0; r < 32; r += 8)
        tile[ty + r][tx] = kp[(size_t)(b * TK + j0 + ty + r) * UU + u0 + tx];
    __syncthreads();
    #pragma unroll
    for (int r = 0; r < 32; r += 8)
        kT[(size_t)(b * UU + u0 + ty + r) * TK + j0 + tx] = tile[tx][ty + r];
}

// One block per (b, RQ q-rows); 512 threads, thread t = column j.
// shifted_score[r][t] = sum_u scale_u * (-2 / (1 + 2^(qs+kT)))  (softmax shift-invariant:
// true score differs by the constant sum_u scale_u). Then row softmax, coalesced store.
__global__ __launch_bounds__(512) void attn_softmax(
    const float* __restrict__ qp,    // [BB, TQ, UU], pre-scaled by 2log2e
    const float* __restrict__ kT,    // [BB, UU, TK], pre-scaled by 2log2e
    const float* __restrict__ scale, // [UU]
    float* __restrict__ out)         // [BB, TQ, TK]
{
    __shared__ float redbuf[RQ][8];

    const int t  = threadIdx.x;
    const int b  = blockIdx.x >> 7;             // TQ/RQ = 128 blocks per b
    const int q0 = (blockIdx.x & 127) * RQ;

    const float* qrow = qp + (size_t)(b * TQ + q0) * UU;   // wave-uniform reads
    const float* kb   = kT + (size_t)b * UU * TK + t;

    float acc[RQ] = {};
    for (int u = 0; u < UU; u += 4) {
        const float4 sc4 = *(const float4*)&scale[u];      // wave-uniform
        float4 q4[RQ];
        #pragma unroll
        for (int r = 0; r < RQ; r++)
            q4[r] = *(const float4*)&qrow[(size_t)r * UU + u];  // wave-uniform
        float kv[4];
        #pragma unroll
        for (int j = 0; j < 4; j++)
            kv[j] = kb[(size_t)(u + j) * TK];              // coalesced, L2-resident
        #pragma unroll
        for (int j = 0; j < 4; j++) {
            const float s = ((const float*)&sc4)[j];
            #pragma unroll
            for (int r = 0; r < RQ; r++) {
                const float x = ((const float*)&q4[r])[j] + kv[j];
                const float e = fexp2(x);                  // e^{2y} = 2^x
                const float d = fmaf(-0.5f, e, -0.5f);     // -(1+e)/2
                acc[r] = fmaf(s, frcp(d), acc[r]);         // += scale * (-2/(1+e))
            }
        }
    }

    const int wave = t >> 6, lane = t & 63;
    float m[RQ], p[RQ];

    // row max over 512 threads
    #pragma unroll
    for (int r = 0; r < RQ; r++) {
        float v = acc[r];
        #pragma unroll
        for (int o = 32; o > 0; o >>= 1) v = fmaxf(v, __shfl_xor(v, o));
        if (lane == 0) redbuf[r][wave] = v;
    }
    __syncthreads();
    #pragma unroll
    for (int r = 0; r < RQ; r++) {
        float v = redbuf[r][0];
        #pragma unroll
        for (int w = 1; w < 8; w++) v = fmaxf(v, redbuf[r][w]);
        m[r] = v;
    }
    __syncthreads();

    // exp and row sum
    #pragma unroll
    for (int r = 0; r < RQ; r++) {
        p[r] = fexp2(L2E * (acc[r] - m[r]));
        float v = p[r];
        #pragma unroll
        for (int o = 32; o > 0; o >>= 1) v += __shfl_xor(v, o);
        if (lane == 0) redbuf[r][wave] = v;
    }
    __syncthreads();
    #pragma unroll
    for (int r = 0; r < RQ; r++) {
        float v = 0.0f;
        #pragma unroll
        for (int w = 0; w < 8; w++) v += redbuf[r][w];
        const float rinv = frcp(v);
        out[(size_t)(b * TQ + q0 + r) * TK + t] = p[r] * rinv;
    }
}

extern "C" void kernel_launch(void* const* d_in, const int* in_sizes, int n_in,
                              void* d_out, int out_size, void* d_ws, size_t ws_size,
                              hipStream_t stream) {
    const float* query = (const float*)d_in[0];
    const float* value = (const float*)d_in[1];
    const float* W1    = (const float*)d_in[2];
    const float* W2    = (const float*)d_in[3];
    const float* scale = (const float*)d_in[4];
    float* out = (float*)d_out;

    float* qp = (float*)d_ws;                     // [BB,TQ,UU]  2 MB
    float* kp = qp + (size_t)BB * TQ * UU;        // [BB,TK,UU]  2 MB
    float* kT = kp + (size_t)BB * TK * UU;        // [BB,UU,TK]  2 MB

    proj<<<dim3((BB * TQ) / RM, 1, 2), 256, 0, stream>>>(query, value, W1, W2, qp, kp);
    transpose_k<<<dim3(TK / 32, UU / 32, BB), dim3(32, 8), 0, stream>>>(kp, kT);
    attn_softmax<<<dim3(BB * TQ / RQ), 512, 0, stream>>>(qp, kT, scale, out);
}